// Round 11
// baseline (1578.925 us; speedup 1.0000x reference)
//
#include <hip/hip_runtime.h>

#define NB 512
#define NT 256
#define NI 32
#define NH 128
#define NG 512

typedef __attribute__((ext_vector_type(8))) short bf16x8;
typedef __attribute__((ext_vector_type(4))) float f32x4;

__device__ __forceinline__ float fsig(float x) { return 1.0f / (1.0f + __expf(-x)); }
__device__ __forceinline__ float ftanh(float x) {
    float ax = fabsf(x);
    float e  = __expf(-2.0f * ax);
    float t  = (1.0f - e) / (1.0f + e);
    return copysignf(t, x);
}
__device__ __forceinline__ unsigned short f2bf_rne(float f) {
    unsigned u = __float_as_uint(f);
    return (unsigned short)((u + 0x7FFFu + ((u >> 16) & 1u)) >> 16);
}
__device__ __forceinline__ void split2(float a, float b, unsigned& hi, unsigned& lo) {
    unsigned short ha = f2bf_rne(a), hb = f2bf_rne(b);
    float ra = a - __uint_as_float((unsigned)ha << 16);
    float rb = b - __uint_as_float((unsigned)hb << 16);
    hi = (unsigned)ha | ((unsigned)hb << 16);
    lo = (unsigned)f2bf_rne(ra) | ((unsigned)f2bf_rne(rb) << 16);
}
__device__ __forceinline__ bf16x8 u4bf(uint4 u) {
    union { uint4 u; bf16x8 v; } c; c.u = u; return c.v;
}
// pack one h value: low16 = hi limb, high16 = lo limb
__device__ __forceinline__ unsigned packh(float h) {
    unsigned short hi = f2bf_rne(h);
    float r = h - __uint_as_float((unsigned)hi << 16);
    return (unsigned)hi | ((unsigned)f2bf_rne(r) << 16);
}
#define MFMA16(accv, av, bv) \
    accv = __builtin_amdgcn_mfma_f32_16x16x32_bf16(av, bv, accv, 0, 0, 0)

// ---------------------------------------------------------------------------
// MFMA LSTM recurrence. 32 blocks x 512 threads; block owns 16 batches.
// Wave wv owns gate types i,f,g,o for j in [16wv,16wv+16): after MFMA each
// lane holds all 4 gates for its 4 (batch,j) pairs in regs; c never leaves
// VGPRs; ONE barrier/step.
// Packed h limbs: U[buf][m][j] = hi|lo<<16. A-frag read for k-chunk q:
//   lane(quad,ml) needs k = 32q + 8*quad + jj' (R8/R9-verified layout) ->
//   dwords U[buf][ml][32q+8quad .. +8).   (R10 BUG: read [8q..8q+8) — the
//   missing quad term k-scrambled the product; absmax 4.9e-3.)
// xg prefetched into regs BEFORE the MFMA chain, added after (latency overlap).
// ---------------------------------------------------------------------------
template<bool WRITE_H>
__global__ __launch_bounds__(512, 1)
void recur(const float* __restrict__ xg,    // [NB*Tc][NG] rows = b*Tc+tl
           const float* __restrict__ w_hh,  // [NG][NH]
           float* __restrict__ hout,        // WRITE_H: rows b*Tc+tl, [NH]
           float* __restrict__ h_state, float* __restrict__ c_state, // [NB][NH]
           int Tc, int first)
{
    __shared__ __align__(16) unsigned short Wl[128][64][8];   // 131072 B
    __shared__ __align__(16) unsigned U[2][16][132];          // 16896 B

    const int tid  = threadIdx.x;
    const int wv   = tid >> 6;
    const int lane = tid & 63;
    const int quad = lane >> 4;
    const int ml   = lane & 15;
    const int bk   = blockIdx.x;
    const int j    = 16 * wv + ml;
    const int lidx = ml * 4 + quad;

    // ---- stage weights: hi -> regs, lo -> LDS (B-op layout, R8-verified) ----
    bf16x8 wh[4][4];
#pragma unroll
    for (int t = 0; t < 4; ++t) {
#pragma unroll
        for (int q = 0; q < 4; ++q) {
            int n = (t * 8 + wv) * 16 + ml;
            const float* s = w_hh + (size_t)n * NH + q * 32 + quad * 8;
            float4 v0 = *(const float4*)s;
            float4 v1 = *(const float4*)(s + 4);
            uint4 H, L;
            split2(v0.x, v0.y, H.x, L.x); split2(v0.z, v0.w, H.y, L.y);
            split2(v1.x, v1.y, H.z, L.z); split2(v1.z, v1.w, H.w, L.w);
            wh[t][q] = u4bf(H);
            *(uint4*)&Wl[(t * 8 + wv) * 4 + q][lidx][0] = L;
        }
    }

    // ---- initial c/h ----
    float cr[4];
#pragma unroll
    for (int r = 0; r < 4; ++r) {
        int m = quad * 4 + r;
        float h = 0.f, c = 0.f;
        if (!first) {
            h = h_state[(size_t)(bk * 16 + m) * NH + j];
            c = c_state[(size_t)(bk * 16 + m) * NH + j];
        }
        cr[r] = c;
        U[0][m][j] = packh(h);
    }
    __syncthreads();

    const size_t rs = (size_t)Tc * NG;
    const size_t rowb0 = ((size_t)(bk * 16 + quad * 4) * Tc) * NG + j;

    for (int tl = 0; tl < Tc; ++tl) {
        const int buf = tl & 1, nbuf = buf ^ 1;
        const size_t rowb = rowb0 + (size_t)tl * NG;

        // explicit xg prefetch (issues before the MFMA chain)
        float xgv[4][4];
#pragma unroll
        for (int t = 0; t < 4; ++t)
#pragma unroll
            for (int r = 0; r < 4; ++r)
                xgv[t][r] = xg[rowb + (size_t)r * rs + t * 128];

        f32x4 acc[4] = {};

        // 48 MFMAs: 4 k-chunks x 4 gate types x 3 split terms
#pragma unroll
        for (int q = 0; q < 4; ++q) {
            uint4 wA = *(const uint4*)&U[buf][ml][32 * q + 8 * quad];
            uint4 wB = *(const uint4*)&U[buf][ml][32 * q + 8 * quad + 4];
            uint4 AH, AL;
            AH.x = (wA.x & 0xffffu) | (wA.y << 16);
            AH.y = (wA.z & 0xffffu) | (wA.w << 16);
            AH.z = (wB.x & 0xffffu) | (wB.y << 16);
            AH.w = (wB.z & 0xffffu) | (wB.w << 16);
            AL.x = (wA.x >> 16) | (wA.y & 0xffff0000u);
            AL.y = (wA.z >> 16) | (wA.w & 0xffff0000u);
            AL.z = (wB.x >> 16) | (wB.y & 0xffff0000u);
            AL.w = (wB.z >> 16) | (wB.w & 0xffff0000u);
            bf16x8 ah = u4bf(AH), al = u4bf(AL);
#pragma unroll
            for (int t = 0; t < 4; ++t) {
                bf16x8 wlv = *(const bf16x8*)&Wl[(t * 8 + wv) * 4 + q][lidx][0];
                MFMA16(acc[t], ah, wh[t][q]);
                MFMA16(acc[t], al, wh[t][q]);
                MFMA16(acc[t], ah, wlv);
            }
        }

        // in-register gate activation + c/h update
#pragma unroll
        for (int r = 0; r < 4; ++r) {
            float gi = fsig (acc[0][r] + xgv[0][r]);
            float gf = fsig (acc[1][r] + xgv[1][r]);
            float gg = ftanh(acc[2][r] + xgv[2][r]);
            float go = fsig (acc[3][r] + xgv[3][r]);
            cr[r] = gf * cr[r] + gi * gg;
            float hn = go * ftanh(cr[r]);
            int m = quad * 4 + r;
            U[nbuf][m][j] = packh(hn);
            if (WRITE_H)
                hout[((size_t)(bk * 16 + m) * Tc + tl) * NH + j] = hn;
            if (tl == Tc - 1) {
                h_state[(size_t)(bk * 16 + m) * NH + j] = hn;
                c_state[(size_t)(bk * 16 + m) * NH + j] = cr[r];
            }
        }
        __syncthreads();
    }
}

// ---------------------------------------------------------------------------
// Split-bf16 MFMA GEMM (UNCHANGED from R8 — verified): C = A @ Bw^T + bias.
// ---------------------------------------------------------------------------
template<int KP, bool SLICED>
__global__ __launch_bounds__(256)
void gemm_mfma(const float* __restrict__ A,
               const float* __restrict__ Bw,
               const float* __restrict__ bi, const float* __restrict__ bh,
               float* __restrict__ C, int t0, int tcShift)
{
    constexpr int K = KP * 32;
    __shared__ __align__(16) unsigned short Ah[4][128][8], Al[4][128][8];
    __shared__ __align__(16) unsigned short Bh[4][64][8],  Bl[4][64][8];
    const int tid  = threadIdx.x;
    const int n0   = blockIdx.x * 64;
    const int m0   = blockIdx.y * 128;
    const int wv   = tid >> 6;
    const int lane = tid & 63;
    const int quad = lane >> 4, ml = lane & 15;

    f32x4 acc[2][4] = {};
    float bias[4];
#pragma unroll
    for (int nt = 0; nt < 4; ++nt) {
        int n = n0 + nt * 16 + ml;
        bias[nt] = bi[n] + bh[n];
    }

    for (int kp = 0; kp < KP; ++kp) {
        if (kp) __syncthreads();
#pragma unroll
        for (int r = 0; r < 2; ++r) {
            int u = tid + 256 * r;
            int m = u >> 2, ck = u & 3;
            size_t abase;
            if (SLICED) {
                int mg = m0 + m;
                int b  = mg >> tcShift, tl = mg & ((1 << tcShift) - 1);
                abase = ((size_t)b * NT + (t0 + tl)) * K;
            } else {
                abase = (size_t)(m0 + m) * K;
            }
            const float* s = A + abase + kp * 32 + ck * 8;
            float4 v0 = *(const float4*)s;
            float4 v1 = *(const float4*)(s + 4);
            uint4 H, L;
            split2(v0.x, v0.y, H.x, L.x); split2(v0.z, v0.w, H.y, L.y);
            split2(v1.x, v1.y, H.z, L.z); split2(v1.z, v1.w, H.w, L.w);
            *(uint4*)&Ah[ck][m][0] = H;
            *(uint4*)&Al[ck][m][0] = L;
        }
        {
            int n = tid >> 2, ck = tid & 3;
            const float* s = Bw + (size_t)(n0 + n) * K + kp * 32 + ck * 8;
            float4 v0 = *(const float4*)s;
            float4 v1 = *(const float4*)(s + 4);
            uint4 H, L;
            split2(v0.x, v0.y, H.x, L.x); split2(v0.z, v0.w, H.y, L.y);
            split2(v1.x, v1.y, H.z, L.z); split2(v1.z, v1.w, H.w, L.w);
            *(uint4*)&Bh[ck][n][0] = H;
            *(uint4*)&Bl[ck][n][0] = L;
        }
        __syncthreads();

        bf16x8 ah0 = *(const bf16x8*)&Ah[quad][(2 * wv + 0) * 16 + ml][0];
        bf16x8 al0 = *(const bf16x8*)&Al[quad][(2 * wv + 0) * 16 + ml][0];
        bf16x8 ah1 = *(const bf16x8*)&Ah[quad][(2 * wv + 1) * 16 + ml][0];
        bf16x8 al1 = *(const bf16x8*)&Al[quad][(2 * wv + 1) * 16 + ml][0];
#pragma unroll
        for (int nt = 0; nt < 4; ++nt) {
            bf16x8 bhv = *(const bf16x8*)&Bh[quad][nt * 16 + ml][0];
            bf16x8 blv = *(const bf16x8*)&Bl[quad][nt * 16 + ml][0];
            MFMA16(acc[0][nt], ah0, bhv);
            MFMA16(acc[0][nt], ah0, blv);
            MFMA16(acc[0][nt], al0, bhv);
            MFMA16(acc[1][nt], ah1, bhv);
            MFMA16(acc[1][nt], ah1, blv);
            MFMA16(acc[1][nt], al1, bhv);
        }
    }

#pragma unroll
    for (int mt = 0; mt < 2; ++mt)
#pragma unroll
        for (int nt = 0; nt < 4; ++nt)
#pragma unroll
            for (int reg = 0; reg < 4; ++reg) {
                int m = m0 + (2 * wv + mt) * 16 + quad * 4 + reg;
                int n = n0 + nt * 16 + ml;
                C[(size_t)m * NG + n] = acc[mt][nt][reg] + bias[nt];
            }
}

// ---------------------------------------------------------------------------
// out[b] = fc2_w . relu(fc1_w @ h1_last[b] + fc1_b) + fc2_b
// ---------------------------------------------------------------------------
__global__ void fc_head(const float* __restrict__ h1,
                        const float* __restrict__ fc1w, const float* __restrict__ fc1b,
                        const float* __restrict__ fc2w, const float* __restrict__ fc2b,
                        float* __restrict__ out)
{
    int b = blockIdx.x, j = threadIdx.x;
    const float4* wr = (const float4*)(fc1w + (size_t)j * NH);
    const float4* hv = (const float4*)(h1 + (size_t)b * NH);
    float acc = fc1b[j];
#pragma unroll
    for (int q = 0; q < 32; ++q) {
        float4 w = wr[q], h = hv[q];
        acc += w.x * h.x + w.y * h.y + w.z * h.z + w.w * h.w;
    }
    float z = fmaxf(acc, 0.0f);
    float p = fc2w[j] * z;
#pragma unroll
    for (int off = 32; off > 0; off >>= 1) p += __shfl_down(p, off);
    if (j == 0) out[b] = p + fc2b[0];
}

extern "C" void kernel_launch(void* const* d_in, const int* in_sizes, int n_in,
                              void* d_out, int out_size, void* d_ws, size_t ws_size,
                              hipStream_t stream)
{
    const float* x     = (const float*)d_in[0];
    const float* w_ih0 = (const float*)d_in[1];
    const float* w_hh0 = (const float*)d_in[2];
    const float* b_ih0 = (const float*)d_in[3];
    const float* b_hh0 = (const float*)d_in[4];
    const float* w_ih1 = (const float*)d_in[5];
    const float* w_hh1 = (const float*)d_in[6];
    const float* b_ih1 = (const float*)d_in[7];
    const float* b_hh1 = (const float*)d_in[8];
    const float* fc1w  = (const float*)d_in[9];
    const float* fc1b  = (const float*)d_in[10];
    const float* fc2w  = (const float*)d_in[11];
    const float* fc2b  = (const float*)d_in[12];
    float* out = (float*)d_out;
    float* ws  = (float*)d_ws;

    int Tc = 1;
    for (int cand = 256; cand >= 1; cand >>= 1) {
        size_t need = 4ull * ((size_t)NB * cand * (NG + NH) + 4ull * NB * NH);
        if (need <= ws_size) { Tc = cand; break; }
    }
    int tcShift = __builtin_ctz((unsigned)Tc);

    size_t o_xg  = 0;
    size_t o_h0  = o_xg  + (size_t)NB * Tc * NG;
    size_t o_h0s = o_h0  + (size_t)NB * Tc * NH;
    size_t o_c0s = o_h0s + (size_t)NB * NH;
    size_t o_h1s = o_c0s + (size_t)NB * NH;
    size_t o_c1s = o_h1s + (size_t)NB * NH;

    const int M = NB * Tc;
    const int nchunk = NT / Tc;
    for (int c = 0; c < nchunk; ++c) {
        gemm_mfma<1, true><<<dim3(8, M / 128), 256, 0, stream>>>(
            x, w_ih0, b_ih0, b_hh0, ws + o_xg, c * Tc, tcShift);
        recur<true><<<32, 512, 0, stream>>>(
            ws + o_xg, w_hh0, ws + o_h0, ws + o_h0s, ws + o_c0s, Tc, c == 0);
        gemm_mfma<4, false><<<dim3(8, M / 128), 256, 0, stream>>>(
            ws + o_h0, w_ih1, b_ih1, b_hh1, ws + o_xg, 0, 0);
        recur<false><<<32, 512, 0, stream>>>(
            ws + o_xg, w_hh1, nullptr, ws + o_h1s, ws + o_c1s, Tc, c == 0);
    }
    fc_head<<<NB, 64, 0, stream>>>(ws + o_h1s, fc1w, fc1b, fc2w, fc2b, out);
}

// Round 12
// 1577.936 us; speedup vs baseline: 1.0006x; 1.0006x over previous
//
#include <hip/hip_runtime.h>

#define NB 512
#define NT 256
#define NI 32
#define NH 128
#define NG 512
#define DH 8      // h0 ring depth (steps)
#define DX 8      // xg1 ring depth (steps)

typedef __attribute__((ext_vector_type(8))) short bf16x8;
typedef __attribute__((ext_vector_type(4))) float f32x4;

__device__ __forceinline__ float fsig(float x) { return 1.0f / (1.0f + __expf(-x)); }
__device__ __forceinline__ float ftanh(float x) {
    float ax = fabsf(x);
    float e  = __expf(-2.0f * ax);
    float t  = (1.0f - e) / (1.0f + e);
    return copysignf(t, x);
}
__device__ __forceinline__ unsigned short f2bf_rne(float f) {
    unsigned u = __float_as_uint(f);
    return (unsigned short)((u + 0x7FFFu + ((u >> 16) & 1u)) >> 16);
}
__device__ __forceinline__ void split2(float a, float b, unsigned& hi, unsigned& lo) {
    unsigned short ha = f2bf_rne(a), hb = f2bf_rne(b);
    float ra = a - __uint_as_float((unsigned)ha << 16);
    float rb = b - __uint_as_float((unsigned)hb << 16);
    hi = (unsigned)ha | ((unsigned)hb << 16);
    lo = (unsigned)f2bf_rne(ra) | ((unsigned)f2bf_rne(rb) << 16);
}
__device__ __forceinline__ bf16x8 u4bf(uint4 u) {
    union { uint4 u; bf16x8 v; } c; c.u = u; return c.v;
}
__device__ __forceinline__ unsigned packh(float h) {
    unsigned short hi = f2bf_rne(h);
    float r = h - __uint_as_float((unsigned)hi << 16);
    return (unsigned)hi | ((unsigned)f2bf_rne(r) << 16);
}
#define MFMA16(accv, av, bv) \
    accv = __builtin_amdgcn_mfma_f32_16x16x32_bf16(av, bv, accv, 0, 0, 0)

// flag helpers: agent scope (cross-XCD safe)
__device__ __forceinline__ void fl_store(unsigned* f, unsigned v, bool rel) {
    __hip_atomic_store(f, v, rel ? __ATOMIC_RELEASE : __ATOMIC_RELAXED,
                       __HIP_MEMORY_SCOPE_AGENT);
}
__device__ __forceinline__ int fl_load(unsigned* f) {
    return (int)__hip_atomic_load(f, __ATOMIC_ACQUIRE, __HIP_MEMORY_SCOPE_AGENT);
}
__device__ __forceinline__ void gstore(float* p, float v) {
    __hip_atomic_store((unsigned*)p, __float_as_uint(v), __ATOMIC_RELAXED,
                       __HIP_MEMORY_SCOPE_AGENT);
}
__device__ __forceinline__ float gload(const float* p) {
    return __uint_as_float(__hip_atomic_load((const unsigned*)p, __ATOMIC_RELAXED,
                                             __HIP_MEMORY_SCOPE_AGENT));
}

// 48-MFMA core: acc[t] += hU @ (wh|Wl) for 4 gate-type n-tiles (t*8+wv).
// Ub rows are packed h dwords (hi|lo): lane(quad,ml) -> A[m=ml][k=32q+8quad+..]
__device__ __forceinline__ void do_mfma48(f32x4 acc[4],
        const unsigned (* __restrict__ Ub)[132],
        const bf16x8 wh[4][4],
        const unsigned short (* __restrict__ Wlp)[64][8],
        int wv, int quad, int ml, int lidx)
{
#pragma unroll
    for (int q = 0; q < 4; ++q) {
        uint4 wA = *(const uint4*)&Ub[ml][32 * q + 8 * quad];
        uint4 wB = *(const uint4*)&Ub[ml][32 * q + 8 * quad + 4];
        uint4 AH, AL;
        AH.x = (wA.x & 0xffffu) | (wA.y << 16);
        AH.y = (wA.z & 0xffffu) | (wA.w << 16);
        AH.z = (wB.x & 0xffffu) | (wB.y << 16);
        AH.w = (wB.z & 0xffffu) | (wB.w << 16);
        AL.x = (wA.x >> 16) | (wA.y & 0xffff0000u);
        AL.y = (wA.z >> 16) | (wA.w & 0xffff0000u);
        AL.z = (wB.x >> 16) | (wB.y & 0xffff0000u);
        AL.w = (wB.z >> 16) | (wB.w & 0xffff0000u);
        bf16x8 ah = u4bf(AH), al = u4bf(AL);
#pragma unroll
        for (int t = 0; t < 4; ++t) {
            bf16x8 wlv = *(const bf16x8*)&Wlp[(t * 8 + wv) * 4 + q][lidx][0];
            MFMA16(acc[t], ah, wh[t][q]);
            MFMA16(acc[t], al, wh[t][q]);
            MFMA16(acc[t], ah, wlv);
        }
    }
}

// ---------------------------------------------------------------------------
// 3-stage step-pipelined kernel, 96 blocks x 512 threads:
//  role 0 (blk 0-31):  layer-0 recurrence (reads xg0 chunk buf) -> h0 ring
//  role 1 (blk 32-63): per-step gemm xg1 = h0 @ w_ih1^T + bias  -> xg1 ring
//  role 2 (blk 64-95): layer-1 recurrence (consumes xg1 ring)
// Block p of each role handles batches [16p,16p+16). All 96 blocks resident
// (1 blk/CU), so spin-waits are deadlock-free; rings give backpressure.
// Flags monotonic in absolute step s = base+tl; zeroed once per launch.
// ---------------------------------------------------------------------------
__global__ __launch_bounds__(512, 1)
void pipe(const float* __restrict__ xg0,
          const float* __restrict__ w_hh0,
          const float* __restrict__ w_ih1,
          const float* __restrict__ bi1, const float* __restrict__ bh1,
          const float* __restrict__ w_hh1,
          float* __restrict__ hring, float* __restrict__ xring,
          unsigned* __restrict__ flags,
          float* __restrict__ h0s, float* __restrict__ c0s,
          float* __restrict__ h1s, float* __restrict__ c1s,
          int Tc, int base, int first)
{
    __shared__ __align__(16) unsigned short Wl[128][64][8];  // 131072 B
    __shared__ __align__(16) unsigned U[2][16][132];         // 16896 B

    const int role = blockIdx.x >> 5;
    const int p    = blockIdx.x & 31;
    const int tid  = threadIdx.x;
    const int wv   = tid >> 6;
    const int lane = tid & 63;
    const int quad = lane >> 4;
    const int ml   = lane & 15;
    const int j    = 16 * wv + ml;
    const int lidx = ml * 4 + quad;

    unsigned* fA  = flags + 0 * 1024 + p * 32;  // A: h0[s] published
    unsigned* fBd = flags + 1 * 1024 + p * 32;  // B: h0[s] consumed
    unsigned* fX  = flags + 2 * 1024 + p * 32;  // B: xg1[s] published
    unsigned* fCd = flags + 3 * 1024 + p * 32;  // C: xg1[s] consumed

    // ---- stage weights: hi -> regs, lo -> LDS ----
    const float* wsrc = (role == 0) ? w_hh0 : (role == 1) ? w_ih1 : w_hh1;
    bf16x8 wh[4][4];
#pragma unroll
    for (int t = 0; t < 4; ++t) {
#pragma unroll
        for (int q = 0; q < 4; ++q) {
            int n = (t * 8 + wv) * 16 + ml;
            const float* s = wsrc + (size_t)n * NH + q * 32 + quad * 8;
            float4 v0 = *(const float4*)s;
            float4 v1 = *(const float4*)(s + 4);
            uint4 H, L;
            split2(v0.x, v0.y, H.x, L.x); split2(v0.z, v0.w, H.y, L.y);
            split2(v1.x, v1.y, H.z, L.z); split2(v1.z, v1.w, H.w, L.w);
            wh[t][q] = u4bf(H);
            *(uint4*)&Wl[(t * 8 + wv) * 4 + q][lidx][0] = L;
        }
    }

    float bias4[4];
    if (role == 1) {
#pragma unroll
        for (int t = 0; t < 4; ++t) {
            int g = t * 128 + j;
            bias4[t] = bi1[g] + bh1[g];
        }
    }

    float cr[4] = {};
    if (role != 1) {
        const float* hs = (role == 0) ? h0s : h1s;
        const float* cs = (role == 0) ? c0s : c1s;
#pragma unroll
        for (int r = 0; r < 4; ++r) {
            int m = quad * 4 + r;
            float h = 0.f, c = 0.f;
            if (!first) {
                h = hs[(size_t)(p * 16 + m) * NH + j];
                c = cs[(size_t)(p * 16 + m) * NH + j];
            }
            cr[r] = c;
            U[0][m][j] = packh(h);
        }
    }
    __syncthreads();

    if (role == 0) {
        // ================= layer-0 recurrence =================
        const size_t rs = (size_t)Tc * NG;
        const size_t rowb0 = ((size_t)(p * 16 + quad * 4) * Tc) * NG + j;
        for (int tl = 0; tl < Tc; ++tl) {
            const int s = base + tl;
            const int buf = tl & 1, nbuf = buf ^ 1;
            const size_t rowb = rowb0 + (size_t)tl * NG;
            float xgv[4][4];
#pragma unroll
            for (int t = 0; t < 4; ++t)
#pragma unroll
                for (int r = 0; r < 4; ++r)
                    xgv[t][r] = xg0[rowb + (size_t)r * rs + t * 128];

            f32x4 acc[4] = {};
            do_mfma48(acc, U[buf], wh, Wl, wv, quad, ml, lidx);

            float* hslot = hring + ((size_t)(p * DH + (s & (DH - 1))) * 16) * NH;
#pragma unroll
            for (int r = 0; r < 4; ++r) {
                float gi = fsig (acc[0][r] + xgv[0][r]);
                float gf = fsig (acc[1][r] + xgv[1][r]);
                float gg = ftanh(acc[2][r] + xgv[2][r]);
                float go = fsig (acc[3][r] + xgv[3][r]);
                cr[r] = gf * cr[r] + gi * gg;
                float hn = go * ftanh(cr[r]);
                int m = quad * 4 + r;
                U[nbuf][m][j] = packh(hn);
                gstore(hslot + (size_t)m * NH + j, hn);
                if (tl == Tc - 1) {
                    h0s[(size_t)(p * 16 + m) * NH + j] = hn;
                    c0s[(size_t)(p * 16 + m) * NH + j] = cr[r];
                }
            }
            __syncthreads();            // drains ring stores (vmcnt) + U
            if (tid == 0) {
                fl_store(fA, (unsigned)(s + 1), true);
                while (fl_load(fBd) < s + 2 - DH) __builtin_amdgcn_s_sleep(1);
            }
            __syncthreads();
        }
    } else if (role == 1) {
        // ================= per-step gemm xg1 = h0 @ w_ih1^T + bias ==========
        for (int tl = 0; tl < Tc; ++tl) {
            const int s = base + tl;
            if (tid == 0) {
                while (fl_load(fA) < s + 1) __builtin_amdgcn_s_sleep(1);
                while (fl_load(fCd) < s + 2 - DX) __builtin_amdgcn_s_sleep(1);
            }
            __syncthreads();
            const float* hslot = hring + ((size_t)(p * DH + (s & (DH - 1))) * 16) * NH;
#pragma unroll
            for (int r = 0; r < 4; ++r) {
                int m = quad * 4 + r;
                U[0][m][j] = packh(gload(hslot + (size_t)m * NH + j));
            }
            __syncthreads();
            if (tid == 0) fl_store(fBd, (unsigned)(s + 1), true);

            f32x4 acc[4] = {};
            do_mfma48(acc, U[0], wh, Wl, wv, quad, ml, lidx);

            float* xslot = xring + ((size_t)(p * DX + (s & (DX - 1))) * 16) * NG;
#pragma unroll
            for (int t = 0; t < 4; ++t)
#pragma unroll
                for (int r = 0; r < 4; ++r)
                    gstore(xslot + (size_t)(quad * 4 + r) * NG + t * 128 + j,
                           acc[t][r] + bias4[t]);
            __syncthreads();            // drains xg1 stores
            if (tid == 0) fl_store(fX, (unsigned)(s + 1), true);
        }
    } else {
        // ================= layer-1 recurrence =================
        for (int tl = 0; tl < Tc; ++tl) {
            const int s = base + tl;
            const int buf = tl & 1, nbuf = buf ^ 1;
            if (tid == 0) {
                while (fl_load(fX) < s + 1) __builtin_amdgcn_s_sleep(1);
            }
            __syncthreads();
            const float* xslot = xring + ((size_t)(p * DX + (s & (DX - 1))) * 16) * NG;
            float xgv[4][4];
#pragma unroll
            for (int t = 0; t < 4; ++t)
#pragma unroll
                for (int r = 0; r < 4; ++r)
                    xgv[t][r] = gload(xslot + (size_t)(quad * 4 + r) * NG + t * 128 + j);

            f32x4 acc[4] = {};
            do_mfma48(acc, U[buf], wh, Wl, wv, quad, ml, lidx);

#pragma unroll
            for (int r = 0; r < 4; ++r) {
                float gi = fsig (acc[0][r] + xgv[0][r]);
                float gf = fsig (acc[1][r] + xgv[1][r]);
                float gg = ftanh(acc[2][r] + xgv[2][r]);
                float go = fsig (acc[3][r] + xgv[3][r]);
                cr[r] = gf * cr[r] + gi * gg;
                float hn = go * ftanh(cr[r]);
                int m = quad * 4 + r;
                U[nbuf][m][j] = packh(hn);
                if (tl == Tc - 1) {
                    h1s[(size_t)(p * 16 + m) * NH + j] = hn;
                    c1s[(size_t)(p * 16 + m) * NH + j] = cr[r];
                }
            }
            __syncthreads();            // xgv consumed; U[nbuf] ready
            if (tid == 0) fl_store(fCd, (unsigned)(s + 1), false);
        }
    }
}

// ---------------------------------------------------------------------------
// Split-bf16 MFMA GEMM (R8-verified), used for xg0 = x @ w_ih0^T + bias.
// ---------------------------------------------------------------------------
template<int KP, bool SLICED>
__global__ __launch_bounds__(256)
void gemm_mfma(const float* __restrict__ A,
               const float* __restrict__ Bw,
               const float* __restrict__ bi, const float* __restrict__ bh,
               float* __restrict__ C, int t0, int tcShift)
{
    constexpr int K = KP * 32;
    __shared__ __align__(16) unsigned short Ah[4][128][8], Al[4][128][8];
    __shared__ __align__(16) unsigned short Bh[4][64][8],  Bl[4][64][8];
    const int tid  = threadIdx.x;
    const int n0   = blockIdx.x * 64;
    const int m0   = blockIdx.y * 128;
    const int wv   = tid >> 6;
    const int lane = tid & 63;
    const int quad = lane >> 4, ml = lane & 15;

    f32x4 acc[2][4] = {};
    float bias[4];
#pragma unroll
    for (int nt = 0; nt < 4; ++nt) {
        int n = n0 + nt * 16 + ml;
        bias[nt] = bi[n] + bh[n];
    }

    for (int kp = 0; kp < KP; ++kp) {
        if (kp) __syncthreads();
#pragma unroll
        for (int r = 0; r < 2; ++r) {
            int u = tid + 256 * r;
            int m = u >> 2, ck = u & 3;
            size_t abase;
            if (SLICED) {
                int mg = m0 + m;
                int b  = mg >> tcShift, tl = mg & ((1 << tcShift) - 1);
                abase = ((size_t)b * NT + (t0 + tl)) * K;
            } else {
                abase = (size_t)(m0 + m) * K;
            }
            const float* s = A + abase + kp * 32 + ck * 8;
            float4 v0 = *(const float4*)s;
            float4 v1 = *(const float4*)(s + 4);
            uint4 H, L;
            split2(v0.x, v0.y, H.x, L.x); split2(v0.z, v0.w, H.y, L.y);
            split2(v1.x, v1.y, H.z, L.z); split2(v1.z, v1.w, H.w, L.w);
            *(uint4*)&Ah[ck][m][0] = H;
            *(uint4*)&Al[ck][m][0] = L;
        }
        {
            int n = tid >> 2, ck = tid & 3;
            const float* s = Bw + (size_t)(n0 + n) * K + kp * 32 + ck * 8;
            float4 v0 = *(const float4*)s;
            float4 v1 = *(const float4*)(s + 4);
            uint4 H, L;
            split2(v0.x, v0.y, H.x, L.x); split2(v0.z, v0.w, H.y, L.y);
            split2(v1.x, v1.y, H.z, L.z); split2(v1.z, v1.w, H.w, L.w);
            *(uint4*)&Bh[ck][n][0] = H;
            *(uint4*)&Bl[ck][n][0] = L;
        }
        __syncthreads();

        bf16x8 ah0 = *(const bf16x8*)&Ah[quad][(2 * wv + 0) * 16 + ml][0];
        bf16x8 al0 = *(const bf16x8*)&Al[quad][(2 * wv + 0) * 16 + ml][0];
        bf16x8 ah1 = *(const bf16x8*)&Ah[quad][(2 * wv + 1) * 16 + ml][0];
        bf16x8 al1 = *(const bf16x8*)&Al[quad][(2 * wv + 1) * 16 + ml][0];
#pragma unroll
        for (int nt = 0; nt < 4; ++nt) {
            bf16x8 bhv = *(const bf16x8*)&Bh[quad][nt * 16 + ml][0];
            bf16x8 blv = *(const bf16x8*)&Bl[quad][nt * 16 + ml][0];
            MFMA16(acc[0][nt], ah0, bhv);
            MFMA16(acc[0][nt], ah0, blv);
            MFMA16(acc[0][nt], al0, bhv);
            MFMA16(acc[1][nt], ah1, bhv);
            MFMA16(acc[1][nt], ah1, blv);
            MFMA16(acc[1][nt], al1, bhv);
        }
    }

#pragma unroll
    for (int mt = 0; mt < 2; ++mt)
#pragma unroll
        for (int nt = 0; nt < 4; ++nt)
#pragma unroll
            for (int reg = 0; reg < 4; ++reg) {
                int m = m0 + (2 * wv + mt) * 16 + quad * 4 + reg;
                int n = n0 + nt * 16 + ml;
                C[(size_t)m * NG + n] = acc[mt][nt][reg] + bias[nt];
            }
}

// ---------------------------------------------------------------------------
// out[b] = fc2_w . relu(fc1_w @ h1_last[b] + fc1_b) + fc2_b
// ---------------------------------------------------------------------------
__global__ void fc_head(const float* __restrict__ h1,
                        const float* __restrict__ fc1w, const float* __restrict__ fc1b,
                        const float* __restrict__ fc2w, const float* __restrict__ fc2b,
                        float* __restrict__ out)
{
    int b = blockIdx.x, j = threadIdx.x;
    const float4* wr = (const float4*)(fc1w + (size_t)j * NH);
    const float4* hv = (const float4*)(h1 + (size_t)b * NH);
    float acc = fc1b[j];
#pragma unroll
    for (int q = 0; q < 32; ++q) {
        float4 w = wr[q], h = hv[q];
        acc += w.x * h.x + w.y * h.y + w.z * h.z + w.w * h.w;
    }
    float z = fmaxf(acc, 0.0f);
    float p = fc2w[j] * z;
#pragma unroll
    for (int off = 32; off > 0; off >>= 1) p += __shfl_down(p, off);
    if (j == 0) out[b] = p + fc2b[0];
}

extern "C" void kernel_launch(void* const* d_in, const int* in_sizes, int n_in,
                              void* d_out, int out_size, void* d_ws, size_t ws_size,
                              hipStream_t stream)
{
    const float* x     = (const float*)d_in[0];
    const float* w_ih0 = (const float*)d_in[1];
    const float* w_hh0 = (const float*)d_in[2];
    const float* b_ih0 = (const float*)d_in[3];
    const float* b_hh0 = (const float*)d_in[4];
    const float* w_ih1 = (const float*)d_in[5];
    const float* w_hh1 = (const float*)d_in[6];
    const float* b_ih1 = (const float*)d_in[7];
    const float* b_hh1 = (const float*)d_in[8];
    const float* fc1w  = (const float*)d_in[9];
    const float* fc1b  = (const float*)d_in[10];
    const float* fc2w  = (const float*)d_in[11];
    const float* fc2b  = (const float*)d_in[12];
    float* out = (float*)d_out;
    float* ws  = (float*)d_ws;

    const size_t ring_f  = (size_t)DH * 32 * 16 * NH + (size_t)DX * 32 * 16 * NG;
    const size_t state_f = 4ull * NB * NH;
    const size_t flag_u  = 4096;

    int Tc = 1;
    for (int cand = 256; cand >= 1; cand >>= 1) {
        size_t need = 4ull * ((size_t)NB * cand * NG + ring_f + state_f + flag_u);
        if (need <= ws_size) { Tc = cand; break; }
    }
    int tcShift = __builtin_ctz((unsigned)Tc);

    size_t o_xg0   = 0;
    size_t o_hring = o_xg0 + (size_t)NB * Tc * NG;
    size_t o_xring = o_hring + (size_t)DH * 32 * 16 * NH;
    size_t o_h0s   = o_xring + (size_t)DX * 32 * 16 * NG;
    size_t o_c0s   = o_h0s + (size_t)NB * NH;
    size_t o_h1s   = o_c0s + (size_t)NB * NH;
    size_t o_c1s   = o_h1s + (size_t)NB * NH;
    size_t o_flags = o_c1s + (size_t)NB * NH;
    unsigned* flags = (unsigned*)(ws + o_flags);

    hipMemsetAsync(flags, 0, flag_u * sizeof(unsigned), stream);

    const int M = NB * Tc;
    const int nchunk = NT / Tc;
    for (int c = 0; c < nchunk; ++c) {
        gemm_mfma<1, true><<<dim3(8, M / 128), 256, 0, stream>>>(
            x, w_ih0, b_ih0, b_hh0, ws + o_xg0, c * Tc, tcShift);
        pipe<<<96, 512, 0, stream>>>(
            ws + o_xg0, w_hh0, w_ih1, b_ih1, b_hh1, w_hh1,
            ws + o_hring, ws + o_xring, flags,
            ws + o_h0s, ws + o_c0s, ws + o_h1s, ws + o_c1s,
            Tc, c * Tc, c == 0);
    }
    fc_head<<<NB, 64, 0, stream>>>(ws + o_h1s, fc1w, fc1b, fc2w, fc2b, out);
}

// Round 13
// 1116.416 us; speedup vs baseline: 1.4143x; 1.4134x over previous
//
#include <hip/hip_runtime.h>

#define NB 512
#define NT 256
#define NI 32
#define NH 128
#define NG 512

typedef __attribute__((ext_vector_type(8))) short bf16x8;
typedef __attribute__((ext_vector_type(4))) float f32x4;

__device__ __forceinline__ float fsig(float x) { return 1.0f / (1.0f + __expf(-x)); }
__device__ __forceinline__ float ftanh(float x) {
    float ax = fabsf(x);
    float e  = __expf(-2.0f * ax);
    float t  = (1.0f - e) / (1.0f + e);
    return copysignf(t, x);
}
__device__ __forceinline__ unsigned short f2bf_rne(float f) {
    unsigned u = __float_as_uint(f);
    return (unsigned short)((u + 0x7FFFu + ((u >> 16) & 1u)) >> 16);
}
__device__ __forceinline__ void split2(float a, float b, unsigned& hi, unsigned& lo) {
    unsigned short ha = f2bf_rne(a), hb = f2bf_rne(b);
    float ra = a - __uint_as_float((unsigned)ha << 16);
    float rb = b - __uint_as_float((unsigned)hb << 16);
    hi = (unsigned)ha | ((unsigned)hb << 16);
    lo = (unsigned)f2bf_rne(ra) | ((unsigned)f2bf_rne(rb) << 16);
}
__device__ __forceinline__ bf16x8 u4bf(uint4 u) {
    union { uint4 u; bf16x8 v; } c; c.u = u; return c.v;
}
__device__ __forceinline__ unsigned packh(float h) {
    unsigned short hi = f2bf_rne(h);
    float r = h - __uint_as_float((unsigned)hi << 16);
    return (unsigned)hi | ((unsigned)f2bf_rne(r) << 16);
}
#define MFMA16(accv, av, bv) \
    accv = __builtin_amdgcn_mfma_f32_16x16x32_bf16(av, bv, accv, 0, 0, 0)

// LDS-only barrier: orders ds ops across waves WITHOUT draining vmcnt.
// (R11's __syncthreads emitted s_waitcnt vmcnt(0) -> waited the 4 hout
// global stores every step. hout/h_state are consumed only at kernel
// boundaries; U-read WAR is covered by lgkmcnt(0).)
__device__ __forceinline__ void lds_barrier() {
    asm volatile("s_waitcnt lgkmcnt(0)\n\ts_barrier" ::: "memory");
}

// ---------------------------------------------------------------------------
// Paired MFMA LSTM recurrence: 64 blocks x 512 threads, ZERO inter-role comms.
//   role 0 (blk  0-31): layer-0 recurrence, chunk i   (reads xg0, writes h0buf)
//   role 1 (blk 32-63): layer-1 recurrence, chunk i-1 (reads xg1)
// Chunks are independent across layers at 1-chunk skew -> 64 CUs busy vs 32.
// Per-role body is R11's verified kernel: wave wv owns gate types i,f,g,o for
// j in [16wv,16wv+16); packed h limbs U[buf][m][j]=hi|lo; A-frag k=32q+8quad;
// 48 MFMAs/step (split-bf16 3-term); c in VGPRs; one barrier/step.
// ---------------------------------------------------------------------------
__global__ __launch_bounds__(512, 1)
void recur_pair(const float* __restrict__ xg0,   // [NB*Tc][NG] rows b*Tc+tl
                const float* __restrict__ xg1,
                const float* __restrict__ w_hh0,
                const float* __restrict__ w_hh1,
                float* __restrict__ h0buf,       // role0 hout
                float* __restrict__ h0s, float* __restrict__ c0s,
                float* __restrict__ h1s, float* __restrict__ c1s,
                int Tc, int doA, int doB, int firstA, int firstB)
{
    __shared__ __align__(16) unsigned short Wl[128][64][8];   // 131072 B
    __shared__ __align__(16) unsigned U[2][16][132];          // 16896 B

    const int role = blockIdx.x >> 5;
    if (role == 0 && !doA) return;
    if (role == 1 && !doB) return;

    const float* xg    = role ? xg1   : xg0;
    const float* wsrc  = role ? w_hh1 : w_hh0;
    float*       hout  = role ? nullptr : h0buf;
    float*       hs    = role ? h1s : h0s;
    float*       cs    = role ? c1s : c0s;
    const int    first = role ? firstB : firstA;

    const int p    = blockIdx.x & 31;
    const int tid  = threadIdx.x;
    const int wv   = tid >> 6;
    const int lane = tid & 63;
    const int quad = lane >> 4;
    const int ml   = lane & 15;
    const int j    = 16 * wv + ml;
    const int lidx = ml * 4 + quad;

    // ---- stage weights: hi -> regs, lo -> LDS ----
    bf16x8 wh[4][4];
#pragma unroll
    for (int t = 0; t < 4; ++t) {
#pragma unroll
        for (int q = 0; q < 4; ++q) {
            int n = (t * 8 + wv) * 16 + ml;
            const float* s = wsrc + (size_t)n * NH + q * 32 + quad * 8;
            float4 v0 = *(const float4*)s;
            float4 v1 = *(const float4*)(s + 4);
            uint4 H, L;
            split2(v0.x, v0.y, H.x, L.x); split2(v0.z, v0.w, H.y, L.y);
            split2(v1.x, v1.y, H.z, L.z); split2(v1.z, v1.w, H.w, L.w);
            wh[t][q] = u4bf(H);
            *(uint4*)&Wl[(t * 8 + wv) * 4 + q][lidx][0] = L;
        }
    }

    // ---- initial c/h ----
    float cr[4];
#pragma unroll
    for (int r = 0; r < 4; ++r) {
        int m = quad * 4 + r;
        float h = 0.f, c = 0.f;
        if (!first) {
            h = hs[(size_t)(p * 16 + m) * NH + j];
            c = cs[(size_t)(p * 16 + m) * NH + j];
        }
        cr[r] = c;
        U[0][m][j] = packh(h);
    }
    __syncthreads();

    const size_t rs = (size_t)Tc * NG;
    const size_t rowb0 = ((size_t)(p * 16 + quad * 4) * Tc) * NG + j;

    for (int tl = 0; tl < Tc; ++tl) {
        const int buf = tl & 1, nbuf = buf ^ 1;
        const size_t rowb = rowb0 + (size_t)tl * NG;

        // xg prefetch (issues before the MFMA chain)
        float xgv[4][4];
#pragma unroll
        for (int t = 0; t < 4; ++t)
#pragma unroll
            for (int r = 0; r < 4; ++r)
                xgv[t][r] = xg[rowb + (size_t)r * rs + t * 128];

        f32x4 acc[4] = {};
#pragma unroll
        for (int q = 0; q < 4; ++q) {
            uint4 wA = *(const uint4*)&U[buf][ml][32 * q + 8 * quad];
            uint4 wB = *(const uint4*)&U[buf][ml][32 * q + 8 * quad + 4];
            uint4 AH, AL;
            AH.x = (wA.x & 0xffffu) | (wA.y << 16);
            AH.y = (wA.z & 0xffffu) | (wA.w << 16);
            AH.z = (wB.x & 0xffffu) | (wB.y << 16);
            AH.w = (wB.z & 0xffffu) | (wB.w << 16);
            AL.x = (wA.x >> 16) | (wA.y & 0xffff0000u);
            AL.y = (wA.z >> 16) | (wA.w & 0xffff0000u);
            AL.z = (wB.x >> 16) | (wB.y & 0xffff0000u);
            AL.w = (wB.z >> 16) | (wB.w & 0xffff0000u);
            bf16x8 ah = u4bf(AH), al = u4bf(AL);
#pragma unroll
            for (int t = 0; t < 4; ++t) {
                bf16x8 wlv = *(const bf16x8*)&Wl[(t * 8 + wv) * 4 + q][lidx][0];
                MFMA16(acc[t], ah, wh[t][q]);
                MFMA16(acc[t], al, wh[t][q]);
                MFMA16(acc[t], ah, wlv);
            }
        }

        // in-register gate activation + c/h update
#pragma unroll
        for (int r = 0; r < 4; ++r) {
            float gi = fsig (acc[0][r] + xgv[0][r]);
            float gf = fsig (acc[1][r] + xgv[1][r]);
            float gg = ftanh(acc[2][r] + xgv[2][r]);
            float go = fsig (acc[3][r] + xgv[3][r]);
            cr[r] = gf * cr[r] + gi * gg;
            float hn = go * ftanh(cr[r]);
            int m = quad * 4 + r;
            U[nbuf][m][j] = packh(hn);
            if (hout)
                hout[((size_t)(p * 16 + m) * Tc + tl) * NH + j] = hn;
            if (tl == Tc - 1) {
                hs[(size_t)(p * 16 + m) * NH + j] = hn;
                cs[(size_t)(p * 16 + m) * NH + j] = cr[r];
            }
        }
        lds_barrier();   // LDS-only: don't drain hout/state global stores
    }
}

// ---------------------------------------------------------------------------
// Split-bf16 MFMA GEMM (R8-verified): C = A @ Bw^T + (bi+bh).
// ---------------------------------------------------------------------------
template<int KP, bool SLICED>
__global__ __launch_bounds__(256)
void gemm_mfma(const float* __restrict__ A,
               const float* __restrict__ Bw,
               const float* __restrict__ bi, const float* __restrict__ bh,
               float* __restrict__ C, int t0, int tcShift)
{
    constexpr int K = KP * 32;
    __shared__ __align__(16) unsigned short Ah[4][128][8], Al[4][128][8];
    __shared__ __align__(16) unsigned short Bh[4][64][8],  Bl[4][64][8];
    const int tid  = threadIdx.x;
    const int n0   = blockIdx.x * 64;
    const int m0   = blockIdx.y * 128;
    const int wv   = tid >> 6;
    const int lane = tid & 63;
    const int quad = lane >> 4, ml = lane & 15;

    f32x4 acc[2][4] = {};
    float bias[4];
#pragma unroll
    for (int nt = 0; nt < 4; ++nt) {
        int n = n0 + nt * 16 + ml;
        bias[nt] = bi[n] + bh[n];
    }

    for (int kp = 0; kp < KP; ++kp) {
        if (kp) __syncthreads();
#pragma unroll
        for (int r = 0; r < 2; ++r) {
            int u = tid + 256 * r;
            int m = u >> 2, ck = u & 3;
            size_t abase;
            if (SLICED) {
                int mg = m0 + m;
                int b  = mg >> tcShift, tl = mg & ((1 << tcShift) - 1);
                abase = ((size_t)b * NT + (t0 + tl)) * K;
            } else {
                abase = (size_t)(m0 + m) * K;
            }
            const float* s = A + abase + kp * 32 + ck * 8;
            float4 v0 = *(const float4*)s;
            float4 v1 = *(const float4*)(s + 4);
            uint4 H, L;
            split2(v0.x, v0.y, H.x, L.x); split2(v0.z, v0.w, H.y, L.y);
            split2(v1.x, v1.y, H.z, L.z); split2(v1.z, v1.w, H.w, L.w);
            *(uint4*)&Ah[ck][m][0] = H;
            *(uint4*)&Al[ck][m][0] = L;
        }
        {
            int n = tid >> 2, ck = tid & 3;
            const float* s = Bw + (size_t)(n0 + n) * K + kp * 32 + ck * 8;
            float4 v0 = *(const float4*)s;
            float4 v1 = *(const float4*)(s + 4);
            uint4 H, L;
            split2(v0.x, v0.y, H.x, L.x); split2(v0.z, v0.w, H.y, L.y);
            split2(v1.x, v1.y, H.z, L.z); split2(v1.z, v1.w, H.w, L.w);
            *(uint4*)&Bh[ck][n][0] = H;
            *(uint4*)&Bl[ck][n][0] = L;
        }
        __syncthreads();

        bf16x8 ah0 = *(const bf16x8*)&Ah[quad][(2 * wv + 0) * 16 + ml][0];
        bf16x8 al0 = *(const bf16x8*)&Al[quad][(2 * wv + 0) * 16 + ml][0];
        bf16x8 ah1 = *(const bf16x8*)&Ah[quad][(2 * wv + 1) * 16 + ml][0];
        bf16x8 al1 = *(const bf16x8*)&Al[quad][(2 * wv + 1) * 16 + ml][0];
#pragma unroll
        for (int nt = 0; nt < 4; ++nt) {
            bf16x8 bhv = *(const bf16x8*)&Bh[quad][nt * 16 + ml][0];
            bf16x8 blv = *(const bf16x8*)&Bl[quad][nt * 16 + ml][0];
            MFMA16(acc[0][nt], ah0, bhv);
            MFMA16(acc[0][nt], ah0, blv);
            MFMA16(acc[0][nt], al0, bhv);
            MFMA16(acc[1][nt], ah1, bhv);
            MFMA16(acc[1][nt], ah1, blv);
            MFMA16(acc[1][nt], al1, bhv);
        }
    }

#pragma unroll
    for (int mt = 0; mt < 2; ++mt)
#pragma unroll
        for (int nt = 0; nt < 4; ++nt)
#pragma unroll
            for (int reg = 0; reg < 4; ++reg) {
                int m = m0 + (2 * wv + mt) * 16 + quad * 4 + reg;
                int n = n0 + nt * 16 + ml;
                C[(size_t)m * NG + n] = acc[mt][nt][reg] + bias[nt];
            }
}

// ---------------------------------------------------------------------------
// out[b] = fc2_w . relu(fc1_w @ h1_last[b] + fc1_b) + fc2_b
// ---------------------------------------------------------------------------
__global__ void fc_head(const float* __restrict__ h1,
                        const float* __restrict__ fc1w, const float* __restrict__ fc1b,
                        const float* __restrict__ fc2w, const float* __restrict__ fc2b,
                        float* __restrict__ out)
{
    int b = blockIdx.x, j = threadIdx.x;
    const float4* wr = (const float4*)(fc1w + (size_t)j * NH);
    const float4* hv = (const float4*)(h1 + (size_t)b * NH);
    float acc = fc1b[j];
#pragma unroll
    for (int q = 0; q < 32; ++q) {
        float4 w = wr[q], h = hv[q];
        acc += w.x * h.x + w.y * h.y + w.z * h.z + w.w * h.w;
    }
    float z = fmaxf(acc, 0.0f);
    float p = fc2w[j] * z;
#pragma unroll
    for (int off = 32; off > 0; off >>= 1) p += __shfl_down(p, off);
    if (j == 0) out[b] = p + fc2b[0];
}

extern "C" void kernel_launch(void* const* d_in, const int* in_sizes, int n_in,
                              void* d_out, int out_size, void* d_ws, size_t ws_size,
                              hipStream_t stream)
{
    const float* x     = (const float*)d_in[0];
    const float* w_ih0 = (const float*)d_in[1];
    const float* w_hh0 = (const float*)d_in[2];
    const float* b_ih0 = (const float*)d_in[3];
    const float* b_hh0 = (const float*)d_in[4];
    const float* w_ih1 = (const float*)d_in[5];
    const float* w_hh1 = (const float*)d_in[6];
    const float* b_ih1 = (const float*)d_in[7];
    const float* b_hh1 = (const float*)d_in[8];
    const float* fc1w  = (const float*)d_in[9];
    const float* fc1b  = (const float*)d_in[10];
    const float* fc2w  = (const float*)d_in[11];
    const float* fc2b  = (const float*)d_in[12];
    float* out = (float*)d_out;
    float* ws  = (float*)d_ws;

    // xg0 + xg1 + h0 + 4 state arrays (expect Tc=32 at the known ws budget)
    int Tc = 1;
    for (int cand = 256; cand >= 1; cand >>= 1) {
        size_t need = 4ull * ((size_t)NB * cand * (2 * NG + NH) + 4ull * NB * NH);
        if (need <= ws_size) { Tc = cand; break; }
    }
    int tcShift = __builtin_ctz((unsigned)Tc);

    size_t o_xg0 = 0;
    size_t o_xg1 = o_xg0 + (size_t)NB * Tc * NG;
    size_t o_h0  = o_xg1 + (size_t)NB * Tc * NG;
    size_t o_h0s = o_h0  + (size_t)NB * Tc * NH;
    size_t o_c0s = o_h0s + (size_t)NB * NH;
    size_t o_h1s = o_c0s + (size_t)NB * NH;
    size_t o_c1s = o_h1s + (size_t)NB * NH;

    const int M = NB * Tc;
    const int nchunk = NT / Tc;

    // xg0 for chunk 0
    gemm_mfma<1, true><<<dim3(8, M / 128), 256, 0, stream>>>(
        x, w_ih0, b_ih0, b_hh0, ws + o_xg0, 0, tcShift);

    for (int i = 0; i <= nchunk; ++i) {
        int doA = (i < nchunk), doB = (i >= 1);
        recur_pair<<<64, 512, 0, stream>>>(
            ws + o_xg0, ws + o_xg1, w_hh0, w_hh1, ws + o_h0,
            ws + o_h0s, ws + o_c0s, ws + o_h1s, ws + o_c1s,
            Tc, doA, doB, i == 0, i == 1);
        if (i < nchunk)        // xg1 for chunk i (consumed by role1 next iter)
            gemm_mfma<4, false><<<dim3(8, M / 128), 256, 0, stream>>>(
                ws + o_h0, w_ih1, b_ih1, b_hh1, ws + o_xg1, 0, 0);
        if (i + 1 < nchunk)    // xg0 for chunk i+1 (consumed by role0 next iter)
            gemm_mfma<1, true><<<dim3(8, M / 128), 256, 0, stream>>>(
                x, w_ih0, b_ih0, b_hh0, ws + o_xg0, (i + 1) * Tc, tcShift);
    }
    fc_head<<<NB, 64, 0, stream>>>(ws + o_h1s, fc1w, fc1b, fc2w, fc2b, out);
}

// Round 14
// 1106.980 us; speedup vs baseline: 1.4263x; 1.0085x over previous
//
#include <hip/hip_runtime.h>

#define NB 512
#define NT 256
#define NI 32
#define NH 128
#define NG 512

typedef __attribute__((ext_vector_type(8))) short bf16x8;
typedef __attribute__((ext_vector_type(4))) float f32x4;

__device__ __forceinline__ float fsig(float x) { return 1.0f / (1.0f + __expf(-x)); }
__device__ __forceinline__ float ftanh(float x) {
    float ax = fabsf(x);
    float e  = __expf(-2.0f * ax);
    float t  = (1.0f - e) / (1.0f + e);
    return copysignf(t, x);
}
__device__ __forceinline__ unsigned short f2bf_rne(float f) {
    unsigned u = __float_as_uint(f);
    return (unsigned short)((u + 0x7FFFu + ((u >> 16) & 1u)) >> 16);
}
__device__ __forceinline__ void split2(float a, float b, unsigned& hi, unsigned& lo) {
    unsigned short ha = f2bf_rne(a), hb = f2bf_rne(b);
    float ra = a - __uint_as_float((unsigned)ha << 16);
    float rb = b - __uint_as_float((unsigned)hb << 16);
    hi = (unsigned)ha | ((unsigned)hb << 16);
    lo = (unsigned)f2bf_rne(ra) | ((unsigned)f2bf_rne(rb) << 16);
}
__device__ __forceinline__ bf16x8 u4bf(uint4 u) {
    union { uint4 u; bf16x8 v; } c; c.u = u; return c.v;
}
__device__ __forceinline__ unsigned packh(float h) {
    unsigned short hi = f2bf_rne(h);
    float r = h - __uint_as_float((unsigned)hi << 16);
    return (unsigned)hi | ((unsigned)f2bf_rne(r) << 16);
}
#define MFMA16(accv, av, bv) \
    accv = __builtin_amdgcn_mfma_f32_16x16x32_bf16(av, bv, accv, 0, 0, 0)

// LDS-only barrier: orders ds ops across waves WITHOUT draining vmcnt.
__device__ __forceinline__ void lds_barrier() {
    asm volatile("s_waitcnt lgkmcnt(0)\n\ts_barrier" ::: "memory");
}

// ---------------------------------------------------------------------------
// Paired MFMA LSTM recurrence: 64 blocks x 512 threads, ZERO inter-role comms.
//   role 0 (blk  0-31): layer-0 recurrence, chunk i   (reads xg0, writes h0buf)
//   role 1 (blk 32-63): layer-1 recurrence, chunk i-1 (reads xg1)
// R14 LDS-layout fixes (R13 had 3.34M bank conflicts = ~1630 cyc/blk/step):
//  - Wl slot index: ml*4+quad -> lane. Each lane reads back its OWN fragment
//    (Wl is per-lane persistent spill), so slot choice is free; slot=lane is
//    the canonical dense b128 pattern (byte 16*lane) -> conflict-free.
//  - packed-h: U[m][j] stride-132 scatter -> reader-indexed WA/WB[q][lane][4]:
//    both uint4 A-frag reads are dense (byte 16*lane); the transpose scatter
//    moves to the 4 dword STORES (8-way on 2-cyc store ~ 6 cyc, noise).
//    WA[q][L][dd] = packed h[m=L&15][k=32q+8*(L>>4)+dd], WB same at k+4.
// ---------------------------------------------------------------------------
__global__ __launch_bounds__(512, 1)
void recur_pair(const float* __restrict__ xg0,   // [NB*Tc][NG] rows b*Tc+tl
                const float* __restrict__ xg1,
                const float* __restrict__ w_hh0,
                const float* __restrict__ w_hh1,
                float* __restrict__ h0buf,       // role0 hout
                float* __restrict__ h0s, float* __restrict__ c0s,
                float* __restrict__ h1s, float* __restrict__ c1s,
                int Tc, int doA, int doB, int firstA, int firstB)
{
    __shared__ __align__(16) unsigned short Wl[128][64][8];   // 131072 B
    __shared__ __align__(16) unsigned WA[2][4][64][4];        // 8192 B
    __shared__ __align__(16) unsigned WB[2][4][64][4];        // 8192 B

    const int role = blockIdx.x >> 5;
    if (role == 0 && !doA) return;
    if (role == 1 && !doB) return;

    const float* xg    = role ? xg1   : xg0;
    const float* wsrc  = role ? w_hh1 : w_hh0;
    float*       hout  = role ? nullptr : h0buf;
    float*       hs    = role ? h1s : h0s;
    float*       cs    = role ? c1s : c0s;
    const int    first = role ? firstB : firstA;

    const int p    = blockIdx.x & 31;
    const int tid  = threadIdx.x;
    const int wv   = tid >> 6;
    const int lane = tid & 63;
    const int quad = lane >> 4;
    const int ml   = lane & 15;
    const int j    = 16 * wv + ml;

    // h-store coordinates (uniform in r): j -> (q_s, quad_s, d)
    const int q_s    = j >> 5;
    const int quad_s = (j >> 3) & 3;
    const int dd     = j & 3;
    const bool loA   = (j & 7) < 4;

    // ---- stage weights: hi -> regs, lo -> LDS (slot = lane, dense) ----
    bf16x8 wh[4][4];
#pragma unroll
    for (int t = 0; t < 4; ++t) {
#pragma unroll
        for (int q = 0; q < 4; ++q) {
            int n = (t * 8 + wv) * 16 + ml;
            const float* s = wsrc + (size_t)n * NH + q * 32 + quad * 8;
            float4 v0 = *(const float4*)s;
            float4 v1 = *(const float4*)(s + 4);
            uint4 H, L;
            split2(v0.x, v0.y, H.x, L.x); split2(v0.z, v0.w, H.y, L.y);
            split2(v1.x, v1.y, H.z, L.z); split2(v1.z, v1.w, H.w, L.w);
            wh[t][q] = u4bf(H);
            *(uint4*)&Wl[(t * 8 + wv) * 4 + q][lane][0] = L;
        }
    }

    // ---- initial c/h ----
    float cr[4];
#pragma unroll
    for (int r = 0; r < 4; ++r) {
        int m = quad * 4 + r;
        float h = 0.f, c = 0.f;
        if (!first) {
            h = hs[(size_t)(p * 16 + m) * NH + j];
            c = cs[(size_t)(p * 16 + m) * NH + j];
        }
        cr[r] = c;
        unsigned pv = packh(h);
        if (loA) WA[0][q_s][quad_s * 16 + m][dd] = pv;
        else     WB[0][q_s][quad_s * 16 + m][dd] = pv;
    }
    __syncthreads();

    const size_t rs = (size_t)Tc * NG;
    const size_t rowb0 = ((size_t)(p * 16 + quad * 4) * Tc) * NG + j;

    for (int tl = 0; tl < Tc; ++tl) {
        const int buf = tl & 1, nbuf = buf ^ 1;
        const size_t rowb = rowb0 + (size_t)tl * NG;

        // xg prefetch (issues before the MFMA chain)
        float xgv[4][4];
#pragma unroll
        for (int t = 0; t < 4; ++t)
#pragma unroll
            for (int r = 0; r < 4; ++r)
                xgv[t][r] = xg[rowb + (size_t)r * rs + t * 128];

        f32x4 acc[4] = {};
#pragma unroll
        for (int q = 0; q < 4; ++q) {
            uint4 wAv = *(const uint4*)&WA[buf][q][lane][0];   // dense b128
            uint4 wBv = *(const uint4*)&WB[buf][q][lane][0];   // dense b128
            uint4 AH, AL;
            AH.x = (wAv.x & 0xffffu) | (wAv.y << 16);
            AH.y = (wAv.z & 0xffffu) | (wAv.w << 16);
            AH.z = (wBv.x & 0xffffu) | (wBv.y << 16);
            AH.w = (wBv.z & 0xffffu) | (wBv.w << 16);
            AL.x = (wAv.x >> 16) | (wAv.y & 0xffff0000u);
            AL.y = (wAv.z >> 16) | (wAv.w & 0xffff0000u);
            AL.z = (wBv.x >> 16) | (wBv.y & 0xffff0000u);
            AL.w = (wBv.z >> 16) | (wBv.w & 0xffff0000u);
            bf16x8 ah = u4bf(AH), al = u4bf(AL);
#pragma unroll
            for (int t = 0; t < 4; ++t) {
                bf16x8 wlv = *(const bf16x8*)&Wl[(t * 8 + wv) * 4 + q][lane][0];
                MFMA16(acc[t], ah, wh[t][q]);
                MFMA16(acc[t], al, wh[t][q]);
                MFMA16(acc[t], ah, wlv);
            }
        }

        // in-register gate activation + c/h update
#pragma unroll
        for (int r = 0; r < 4; ++r) {
            float gi = fsig (acc[0][r] + xgv[0][r]);
            float gf = fsig (acc[1][r] + xgv[1][r]);
            float gg = ftanh(acc[2][r] + xgv[2][r]);
            float go = fsig (acc[3][r] + xgv[3][r]);
            cr[r] = gf * cr[r] + gi * gg;
            float hn = go * ftanh(cr[r]);
            int m = quad * 4 + r;
            unsigned pv = packh(hn);
            if (loA) WA[nbuf][q_s][quad_s * 16 + m][dd] = pv;
            else     WB[nbuf][q_s][quad_s * 16 + m][dd] = pv;
            if (hout)
                hout[((size_t)(p * 16 + m) * Tc + tl) * NH + j] = hn;
            if (tl == Tc - 1) {
                hs[(size_t)(p * 16 + m) * NH + j] = hn;
                cs[(size_t)(p * 16 + m) * NH + j] = cr[r];
            }
        }
        lds_barrier();   // LDS-only: don't drain hout/state global stores
    }
}

// ---------------------------------------------------------------------------
// Split-bf16 MFMA GEMM (R8-verified): C = A @ Bw^T + (bi+bh).
// ---------------------------------------------------------------------------
template<int KP, bool SLICED>
__global__ __launch_bounds__(256)
void gemm_mfma(const float* __restrict__ A,
               const float* __restrict__ Bw,
               const float* __restrict__ bi, const float* __restrict__ bh,
               float* __restrict__ C, int t0, int tcShift)
{
    constexpr int K = KP * 32;
    __shared__ __align__(16) unsigned short Ah[4][128][8], Al[4][128][8];
    __shared__ __align__(16) unsigned short Bh[4][64][8],  Bl[4][64][8];
    const int tid  = threadIdx.x;
    const int n0   = blockIdx.x * 64;
    const int m0   = blockIdx.y * 128;
    const int wv   = tid >> 6;
    const int lane = tid & 63;
    const int quad = lane >> 4, ml = lane & 15;

    f32x4 acc[2][4] = {};
    float bias[4];
#pragma unroll
    for (int nt = 0; nt < 4; ++nt) {
        int n = n0 + nt * 16 + ml;
        bias[nt] = bi[n] + bh[n];
    }

    for (int kp = 0; kp < KP; ++kp) {
        if (kp) __syncthreads();
#pragma unroll
        for (int r = 0; r < 2; ++r) {
            int u = tid + 256 * r;
            int m = u >> 2, ck = u & 3;
            size_t abase;
            if (SLICED) {
                int mg = m0 + m;
                int b  = mg >> tcShift, tl = mg & ((1 << tcShift) - 1);
                abase = ((size_t)b * NT + (t0 + tl)) * K;
            } else {
                abase = (size_t)(m0 + m) * K;
            }
            const float* s = A + abase + kp * 32 + ck * 8;
            float4 v0 = *(const float4*)s;
            float4 v1 = *(const float4*)(s + 4);
            uint4 H, L;
            split2(v0.x, v0.y, H.x, L.x); split2(v0.z, v0.w, H.y, L.y);
            split2(v1.x, v1.y, H.z, L.z); split2(v1.z, v1.w, H.w, L.w);
            *(uint4*)&Ah[ck][m][0] = H;
            *(uint4*)&Al[ck][m][0] = L;
        }
        {
            int n = tid >> 2, ck = tid & 3;
            const float* s = Bw + (size_t)(n0 + n) * K + kp * 32 + ck * 8;
            float4 v0 = *(const float4*)s;
            float4 v1 = *(const float4*)(s + 4);
            uint4 H, L;
            split2(v0.x, v0.y, H.x, L.x); split2(v0.z, v0.w, H.y, L.y);
            split2(v1.x, v1.y, H.z, L.z); split2(v1.z, v1.w, H.w, L.w);
            *(uint4*)&Bh[ck][n][0] = H;
            *(uint4*)&Bl[ck][n][0] = L;
        }
        __syncthreads();

        bf16x8 ah0 = *(const bf16x8*)&Ah[quad][(2 * wv + 0) * 16 + ml][0];
        bf16x8 al0 = *(const bf16x8*)&Al[quad][(2 * wv + 0) * 16 + ml][0];
        bf16x8 ah1 = *(const bf16x8*)&Ah[quad][(2 * wv + 1) * 16 + ml][0];
        bf16x8 al1 = *(const bf16x8*)&Al[quad][(2 * wv + 1) * 16 + ml][0];
#pragma unroll
        for (int nt = 0; nt < 4; ++nt) {
            bf16x8 bhv = *(const bf16x8*)&Bh[quad][nt * 16 + ml][0];
            bf16x8 blv = *(const bf16x8*)&Bl[quad][nt * 16 + ml][0];
            MFMA16(acc[0][nt], ah0, bhv);
            MFMA16(acc[0][nt], ah0, blv);
            MFMA16(acc[0][nt], al0, bhv);
            MFMA16(acc[1][nt], ah1, bhv);
            MFMA16(acc[1][nt], ah1, blv);
            MFMA16(acc[1][nt], al1, bhv);
        }
    }

#pragma unroll
    for (int mt = 0; mt < 2; ++mt)
#pragma unroll
        for (int nt = 0; nt < 4; ++nt)
#pragma unroll
            for (int reg = 0; reg < 4; ++reg) {
                int m = m0 + (2 * wv + mt) * 16 + quad * 4 + reg;
                int n = n0 + nt * 16 + ml;
                C[(size_t)m * NG + n] = acc[mt][nt][reg] + bias[nt];
            }
}

// ---------------------------------------------------------------------------
// out[b] = fc2_w . relu(fc1_w @ h1_last[b] + fc1_b) + fc2_b
// ---------------------------------------------------------------------------
__global__ void fc_head(const float* __restrict__ h1,
                        const float* __restrict__ fc1w, const float* __restrict__ fc1b,
                        const float* __restrict__ fc2w, const float* __restrict__ fc2b,
                        float* __restrict__ out)
{
    int b = blockIdx.x, j = threadIdx.x;
    const float4* wr = (const float4*)(fc1w + (size_t)j * NH);
    const float4* hv = (const float4*)(h1 + (size_t)b * NH);
    float acc = fc1b[j];
#pragma unroll
    for (int q = 0; q < 32; ++q) {
        float4 w = wr[q], h = hv[q];
        acc += w.x * h.x + w.y * h.y + w.z * h.z + w.w * h.w;
    }
    float z = fmaxf(acc, 0.0f);
    float p = fc2w[j] * z;
#pragma unroll
    for (int off = 32; off > 0; off >>= 1) p += __shfl_down(p, off);
    if (j == 0) out[b] = p + fc2b[0];
}

extern "C" void kernel_launch(void* const* d_in, const int* in_sizes, int n_in,
                              void* d_out, int out_size, void* d_ws, size_t ws_size,
                              hipStream_t stream)
{
    const float* x     = (const float*)d_in[0];
    const float* w_ih0 = (const float*)d_in[1];
    const float* w_hh0 = (const float*)d_in[2];
    const float* b_ih0 = (const float*)d_in[3];
    const float* b_hh0 = (const float*)d_in[4];
    const float* w_ih1 = (const float*)d_in[5];
    const float* w_hh1 = (const float*)d_in[6];
    const float* b_ih1 = (const float*)d_in[7];
    const float* b_hh1 = (const float*)d_in[8];
    const float* fc1w  = (const float*)d_in[9];
    const float* fc1b  = (const float*)d_in[10];
    const float* fc2w  = (const float*)d_in[11];
    const float* fc2b  = (const float*)d_in[12];
    float* out = (float*)d_out;
    float* ws  = (float*)d_ws;

    // xg0 + xg1 + h0 + 4 state arrays (Tc=32 at the known ws budget)
    int Tc = 1;
    for (int cand = 256; cand >= 1; cand >>= 1) {
        size_t need = 4ull * ((size_t)NB * cand * (2 * NG + NH) + 4ull * NB * NH);
        if (need <= ws_size) { Tc = cand; break; }
    }
    int tcShift = __builtin_ctz((unsigned)Tc);

    size_t o_xg0 = 0;
    size_t o_xg1 = o_xg0 + (size_t)NB * Tc * NG;
    size_t o_h0  = o_xg1 + (size_t)NB * Tc * NG;
    size_t o_h0s = o_h0  + (size_t)NB * Tc * NH;
    size_t o_c0s = o_h0s + (size_t)NB * NH;
    size_t o_h1s = o_c0s + (size_t)NB * NH;
    size_t o_c1s = o_h1s + (size_t)NB * NH;

    const int M = NB * Tc;
    const int nchunk = NT / Tc;

    // xg0 for chunk 0
    gemm_mfma<1, true><<<dim3(8, M / 128), 256, 0, stream>>>(
        x, w_ih0, b_ih0, b_hh0, ws + o_xg0, 0, tcShift);

    for (int i = 0; i <= nchunk; ++i) {
        int doA = (i < nchunk), doB = (i >= 1);
        recur_pair<<<64, 512, 0, stream>>>(
            ws + o_xg0, ws + o_xg1, w_hh0, w_hh1, ws + o_h0,
            ws + o_h0s, ws + o_c0s, ws + o_h1s, ws + o_c1s,
            Tc, doA, doB, i == 0, i == 1);
        if (i < nchunk)        // xg1 for chunk i (consumed by role1 next iter)
            gemm_mfma<4, false><<<dim3(8, M / 128), 256, 0, stream>>>(
                ws + o_h0, w_ih1, b_ih1, b_hh1, ws + o_xg1, 0, 0);
        if (i + 1 < nchunk)    // xg0 for chunk i+1 (consumed by role0 next iter)
            gemm_mfma<1, true><<<dim3(8, M / 128), 256, 0, stream>>>(
                x, w_ih0, b_ih0, b_hh0, ws + o_xg0, (i + 1) * Tc, tcShift);
    }
    fc_head<<<NB, 64, 0, stream>>>(ws + o_h1s, fc1w, fc1b, fc2w, fc2b, out);
}